// Round 1
// baseline (1031.439 us; speedup 1.0000x reference)
//
#include <hip/hip_runtime.h>
#include <math.h>

namespace {
constexpr int Bn = 4, Sn = 1024, En = 1024, Hn = 16, DKn = 64;
constexpr float NEGV = -10000.0f;
constexpr float SCALE = 0.125f;  // 1/sqrt(DK)
}

// ---------------- QKV projection: qkv = x @ qkv_w^T + b, scatter to q/k/v (B,H,S,DK), zero padded rows
__global__ __launch_bounds__(256) void gemm_qkv_kernel(
    const float* __restrict__ x, const float* __restrict__ w,
    const float* __restrict__ bias, const int* __restrict__ kpm,
    float* __restrict__ qkv) {
  __shared__ float As[16][68];
  __shared__ float Bs[16][68];
  const int K = En;
  int tid = threadIdx.x;
  int tx = tid & 15, ty = tid >> 4;
  int m0 = blockIdx.y * 64, n0 = blockIdx.x * 64;
  int lm = tid >> 2, lk = (tid & 3) * 4;
  const float* Ap = x + (size_t)(m0 + lm) * K + lk;
  const float* Bp = w + (size_t)(n0 + lm) * K + lk;
  float acc[4][4] = {};
  for (int k0 = 0; k0 < K; k0 += 16) {
    float4 a4 = *(const float4*)(Ap + k0);
    float4 b4 = *(const float4*)(Bp + k0);
    __syncthreads();
    As[lk + 0][lm] = a4.x; As[lk + 1][lm] = a4.y;
    As[lk + 2][lm] = a4.z; As[lk + 3][lm] = a4.w;
    Bs[lk + 0][lm] = b4.x; Bs[lk + 1][lm] = b4.y;
    Bs[lk + 2][lm] = b4.z; Bs[lk + 3][lm] = b4.w;
    __syncthreads();
#pragma unroll
    for (int kk = 0; kk < 16; ++kk) {
      float4 a = *(const float4*)&As[kk][ty * 4];
      float4 b = *(const float4*)&Bs[kk][tx * 4];
      float av[4] = {a.x, a.y, a.z, a.w};
      float bv[4] = {b.x, b.y, b.z, b.w};
#pragma unroll
      for (int i = 0; i < 4; ++i)
#pragma unroll
        for (int j = 0; j < 4; ++j) acc[i][j] = fmaf(av[i], bv[j], acc[i][j]);
    }
  }
  int which = n0 >> 10;       // 0=q 1=k 2=v
  int e0 = n0 & 1023;
  int h = e0 >> 6;
  int d0 = tx * 4;            // n0 % 64 == 0 so d = tx*4+j
  int bidx = m0 >> 10;        // 64 | 1024 -> whole tile same batch
  float bb[4];
#pragma unroll
  for (int j = 0; j < 4; ++j) bb[j] = bias[n0 + tx * 4 + j];
  float* base = qkv + (size_t)which * ((size_t)Bn * Hn * Sn * DKn) +
                (size_t)(bidx * Hn + h) * Sn * DKn;
#pragma unroll
  for (int i = 0; i < 4; ++i) {
    int gm = m0 + ty * 4 + i;
    int s = gm & (Sn - 1);
    bool masked = kpm[gm] != 0;
    float4 o;
    o.x = masked ? 0.f : acc[i][0] + bb[0];
    o.y = masked ? 0.f : acc[i][1] + bb[1];
    o.z = masked ? 0.f : acc[i][2] + bb[2];
    o.w = masked ? 0.f : acc[i][3] + bb[3];
    *(float4*)(base + (size_t)s * DKn + d0) = o;
  }
}

// ---------------- scores = q @ k^T * scale + attn_mask; kpm cols -> NEG (raw, pre-softmax)
__global__ __launch_bounds__(256) void scores_kernel(
    const float* __restrict__ q, const float* __restrict__ k,
    const float* __restrict__ mask, const int* __restrict__ kpm,
    float* __restrict__ wout) {
  __shared__ float As[16][68];
  __shared__ float Bs[16][68];
  int bh = blockIdx.z;
  int bidx = bh >> 4;
  const float* A = q + (size_t)bh * Sn * DKn;
  const float* Bm = k + (size_t)bh * Sn * DKn;
  int tid = threadIdx.x;
  int tx = tid & 15, ty = tid >> 4;
  int m0 = blockIdx.y * 64, n0 = blockIdx.x * 64;
  int lm = tid >> 2, lk = (tid & 3) * 4;
  const float* Ap = A + (size_t)(m0 + lm) * DKn + lk;
  const float* Bp = Bm + (size_t)(n0 + lm) * DKn + lk;
  float acc[4][4] = {};
  for (int k0 = 0; k0 < DKn; k0 += 16) {
    float4 a4 = *(const float4*)(Ap + k0);
    float4 b4 = *(const float4*)(Bp + k0);
    __syncthreads();
    As[lk + 0][lm] = a4.x; As[lk + 1][lm] = a4.y;
    As[lk + 2][lm] = a4.z; As[lk + 3][lm] = a4.w;
    Bs[lk + 0][lm] = b4.x; Bs[lk + 1][lm] = b4.y;
    Bs[lk + 2][lm] = b4.z; Bs[lk + 3][lm] = b4.w;
    __syncthreads();
#pragma unroll
    for (int kk = 0; kk < 16; ++kk) {
      float4 a = *(const float4*)&As[kk][ty * 4];
      float4 b = *(const float4*)&Bs[kk][tx * 4];
      float av[4] = {a.x, a.y, a.z, a.w};
      float bv[4] = {b.x, b.y, b.z, b.w};
#pragma unroll
      for (int i = 0; i < 4; ++i)
#pragma unroll
        for (int j = 0; j < 4; ++j) acc[i][j] = fmaf(av[i], bv[j], acc[i][j]);
    }
  }
  int kp[4];
#pragma unroll
  for (int j = 0; j < 4; ++j) kp[j] = kpm[bidx * Sn + n0 + tx * 4 + j];
#pragma unroll
  for (int i = 0; i < 4; ++i) {
    int m = m0 + ty * 4 + i;
    const float* mrow = mask + (size_t)m * Sn + n0 + tx * 4;
    float4 o;
    o.x = kp[0] ? NEGV : fmaf(acc[i][0], SCALE, mrow[0]);
    o.y = kp[1] ? NEGV : fmaf(acc[i][1], SCALE, mrow[1]);
    o.z = kp[2] ? NEGV : fmaf(acc[i][2], SCALE, mrow[2]);
    o.w = kp[3] ? NEGV : fmaf(acc[i][3], SCALE, mrow[3]);
    *(float4*)(wout + ((size_t)bh * Sn + m) * Sn + n0 + tx * 4) = o;
  }
}

// ---------------- in-place row softmax over the last dim (1024) of weights
__global__ __launch_bounds__(256) void softmax_kernel(float* __restrict__ w) {
  size_t row = blockIdx.x;
  float4* p = (float4*)(w + row * Sn);
  int tid = threadIdx.x;
  float4 v = p[tid];
  float mx = fmaxf(fmaxf(v.x, v.y), fmaxf(v.z, v.w));
#pragma unroll
  for (int off = 32; off > 0; off >>= 1) mx = fmaxf(mx, __shfl_down(mx, off));
  __shared__ float red[8];
  int wid = tid >> 6, lane = tid & 63;
  if (lane == 0) red[wid] = mx;
  __syncthreads();
  mx = fmaxf(fmaxf(red[0], red[1]), fmaxf(red[2], red[3]));
  v.x = __expf(v.x - mx); v.y = __expf(v.y - mx);
  v.z = __expf(v.z - mx); v.w = __expf(v.w - mx);
  float sm = v.x + v.y + v.z + v.w;
#pragma unroll
  for (int off = 32; off > 0; off >>= 1) sm += __shfl_down(sm, off);
  if (lane == 0) red[4 + wid] = sm;
  __syncthreads();
  sm = (red[4] + red[5]) + (red[6] + red[7]);
  float inv = 1.0f / sm;
  v.x *= inv; v.y *= inv; v.z *= inv; v.w *= inv;
  p[tid] = v;
}

// ---------------- attn_pre[b,s,h*64+d] = P(b,h) @ V(b,h)   (NN GEMM, N=64)
__global__ __launch_bounds__(256) void pv_kernel(
    const float* __restrict__ p, const float* __restrict__ v,
    float* __restrict__ ap) {
  __shared__ float As[16][68];
  __shared__ float Bs[16][68];
  int bh = blockIdx.y;
  int bidx = bh >> 4, h = bh & 15;
  const float* A = p + (size_t)bh * Sn * Sn;
  const float* Bv = v + (size_t)bh * Sn * DKn;
  int tid = threadIdx.x;
  int tx = tid & 15, ty = tid >> 4;
  int m0 = blockIdx.x * 64;
  int lm = tid >> 2, lk = (tid & 3) * 4;
  int lkb = tid >> 4, lnb = (tid & 15) * 4;
  const float* Apt = A + (size_t)(m0 + lm) * Sn + lk;
  float acc[4][4] = {};
  for (int k0 = 0; k0 < Sn; k0 += 16) {
    float4 a4 = *(const float4*)(Apt + k0);
    float4 b4 = *(const float4*)(Bv + (size_t)(k0 + lkb) * DKn + lnb);
    __syncthreads();
    As[lk + 0][lm] = a4.x; As[lk + 1][lm] = a4.y;
    As[lk + 2][lm] = a4.z; As[lk + 3][lm] = a4.w;
    Bs[lkb][lnb + 0] = b4.x; Bs[lkb][lnb + 1] = b4.y;
    Bs[lkb][lnb + 2] = b4.z; Bs[lkb][lnb + 3] = b4.w;
    __syncthreads();
#pragma unroll
    for (int kk = 0; kk < 16; ++kk) {
      float4 a = *(const float4*)&As[kk][ty * 4];
      float4 b = *(const float4*)&Bs[kk][tx * 4];
      float av[4] = {a.x, a.y, a.z, a.w};
      float bv[4] = {b.x, b.y, b.z, b.w};
#pragma unroll
      for (int i = 0; i < 4; ++i)
#pragma unroll
        for (int j = 0; j < 4; ++j) acc[i][j] = fmaf(av[i], bv[j], acc[i][j]);
    }
  }
#pragma unroll
  for (int i = 0; i < 4; ++i) {
    int s = m0 + ty * 4 + i;
    float4 o = {acc[i][0], acc[i][1], acc[i][2], acc[i][3]};
    *(float4*)(ap + (size_t)(bidx * Sn + s) * En + h * DKn + tx * 4) = o;
  }
}

// ---------------- out = attn_pre @ out_w^T + out_b
__global__ __launch_bounds__(256) void gemm_out_kernel(
    const float* __restrict__ a, const float* __restrict__ w,
    const float* __restrict__ bias, float* __restrict__ out) {
  __shared__ float As[16][68];
  __shared__ float Bs[16][68];
  const int K = En;
  int tid = threadIdx.x;
  int tx = tid & 15, ty = tid >> 4;
  int m0 = blockIdx.y * 64, n0 = blockIdx.x * 64;
  int lm = tid >> 2, lk = (tid & 3) * 4;
  const float* Ap = a + (size_t)(m0 + lm) * K + lk;
  const float* Bp = w + (size_t)(n0 + lm) * K + lk;
  float acc[4][4] = {};
  for (int k0 = 0; k0 < K; k0 += 16) {
    float4 a4 = *(const float4*)(Ap + k0);
    float4 b4 = *(const float4*)(Bp + k0);
    __syncthreads();
    As[lk + 0][lm] = a4.x; As[lk + 1][lm] = a4.y;
    As[lk + 2][lm] = a4.z; As[lk + 3][lm] = a4.w;
    Bs[lk + 0][lm] = b4.x; Bs[lk + 1][lm] = b4.y;
    Bs[lk + 2][lm] = b4.z; Bs[lk + 3][lm] = b4.w;
    __syncthreads();
#pragma unroll
    for (int kk = 0; kk < 16; ++kk) {
      float4 a4v = *(const float4*)&As[kk][ty * 4];
      float4 b4v = *(const float4*)&Bs[kk][tx * 4];
      float av[4] = {a4v.x, a4v.y, a4v.z, a4v.w};
      float bv[4] = {b4v.x, b4v.y, b4v.z, b4v.w};
#pragma unroll
      for (int i = 0; i < 4; ++i)
#pragma unroll
        for (int j = 0; j < 4; ++j) acc[i][j] = fmaf(av[i], bv[j], acc[i][j]);
    }
  }
  float bb[4];
#pragma unroll
  for (int j = 0; j < 4; ++j) bb[j] = bias[n0 + tx * 4 + j];
#pragma unroll
  for (int i = 0; i < 4; ++i) {
    int gm = m0 + ty * 4 + i;
    float4 o = {acc[i][0] + bb[0], acc[i][1] + bb[1],
                acc[i][2] + bb[2], acc[i][3] + bb[3]};
    *(float4*)(out + (size_t)gm * En + n0 + tx * 4) = o;
  }
}

extern "C" void kernel_launch(void* const* d_in, const int* in_sizes, int n_in,
                              void* d_out, int out_size, void* d_ws, size_t ws_size,
                              hipStream_t stream) {
  const float* x        = (const float*)d_in[0];
  const float* attnmask = (const float*)d_in[1];
  const int*   kpm      = (const int*)d_in[2];
  const float* qkv_w    = (const float*)d_in[3];
  const float* qkv_b    = (const float*)d_in[4];
  const float* out_w    = (const float*)d_in[5];
  const float* out_b    = (const float*)d_in[6];

  float* out     = (float*)d_out;                       // [B,S,E]
  float* weights = out + (size_t)Bn * Sn * En;          // [B,H,S,S]

  const size_t qkv_elems = (size_t)Bn * Hn * Sn * DKn;  // 4,194,304 each
  float* ws = (float*)d_ws;
  float* q  = ws;
  float* k  = q + qkv_elems;
  float* v  = k + qkv_elems;
  float* ap = v + qkv_elems;                            // attn_pre [B,S,E]

  // 1) QKV projection + bias + padding-zero + transpose to (B,H,S,DK)
  gemm_qkv_kernel<<<dim3(48, 64), 256, 0, stream>>>(x, qkv_w, qkv_b, kpm, ws);
  // 2) raw masked scores into the weights output region
  scores_kernel<<<dim3(16, 16, 64), 256, 0, stream>>>(q, k, attnmask, kpm, weights);
  // 3) in-place softmax (B*H*S rows)
  softmax_kernel<<<dim3(Bn * Hn * Sn), 256, 0, stream>>>(weights);
  // 4) P @ V -> attn_pre in (B,S,E) layout
  pv_kernel<<<dim3(16, 64), 256, 0, stream>>>(weights, v, ap);
  // 5) output projection + bias
  gemm_out_kernel<<<dim3(16, 64), 256, 0, stream>>>(ap, out_w, out_b, out);
}

// Round 2
// 643.535 us; speedup vs baseline: 1.6028x; 1.6028x over previous
//
#include <hip/hip_runtime.h>
#include <math.h>

namespace {
constexpr int Bn = 4, Sn = 1024, En = 1024, Hn = 16, DKn = 64;
constexpr float NEGV = -10000.0f;
constexpr float SCALE = 0.125f;  // 1/sqrt(DK)
constexpr int LDR = 40;          // LDS row stride in bf16 elems (80 B): 2-way bank aliasing only
}

typedef __attribute__((ext_vector_type(8))) short bf16x8;
typedef __attribute__((ext_vector_type(4))) float f32x4;

__device__ inline short f2b(float f) {
  unsigned u = __builtin_bit_cast(unsigned, f);
  u += 0x7fffu + ((u >> 16) & 1u);  // RNE
  return (short)(u >> 16);
}

// ---------------- f32 -> bf16 cast (vectorized) ----------------
__global__ __launch_bounds__(256) void cast_kernel(const float* __restrict__ in,
                                                   short* __restrict__ out, int n4) {
  int i = blockIdx.x * 256 + threadIdx.x;
  if (i < n4) {
    float4 v = ((const float4*)in)[i];
    short4 o = {f2b(v.x), f2b(v.y), f2b(v.z), f2b(v.w)};
    ((short4*)out)[i] = o;
  }
}

// ---------------- QKV: C = xb @ wqb^T + bias, mask rows, scatter bf16 q/k/vT
// 128x128 block tile, 4 waves (2x2), each wave 64x64 via 4x4 MFMA 16x16x32 frags.
__global__ __launch_bounds__(256) void qkv_mfma_kernel(
    const short* __restrict__ xb, const short* __restrict__ wb,
    const float* __restrict__ bias, const int* __restrict__ kpm,
    short* __restrict__ qb, short* __restrict__ kb, short* __restrict__ vtb) {
  __shared__ short As[128 * LDR];
  __shared__ short Bs[128 * LDR];
  const int tid = threadIdx.x;
  const int wave = tid >> 6, lane = tid & 63;
  const int quad = lane >> 4, l16 = lane & 15;
  const int wm = (wave >> 1) * 64, wn = (wave & 1) * 64;
  const int m0 = blockIdx.y * 128, n0 = blockIdx.x * 128;
  const int srow = tid >> 2, scol = (tid & 3) * 8;
  f32x4 acc[4][4];
#pragma unroll
  for (int i = 0; i < 4; ++i)
#pragma unroll
    for (int j = 0; j < 4; ++j) acc[i][j] = (f32x4){0.f, 0.f, 0.f, 0.f};
  for (int k0 = 0; k0 < 1024; k0 += 32) {
    bf16x8 a0 = *(const bf16x8*)(xb + (size_t)(m0 + srow) * 1024 + k0 + scol);
    bf16x8 a1 = *(const bf16x8*)(xb + (size_t)(m0 + srow + 64) * 1024 + k0 + scol);
    bf16x8 b0 = *(const bf16x8*)(wb + (size_t)(n0 + srow) * 1024 + k0 + scol);
    bf16x8 b1 = *(const bf16x8*)(wb + (size_t)(n0 + srow + 64) * 1024 + k0 + scol);
    __syncthreads();
    *(bf16x8*)(As + srow * LDR + scol) = a0;
    *(bf16x8*)(As + (srow + 64) * LDR + scol) = a1;
    *(bf16x8*)(Bs + srow * LDR + scol) = b0;
    *(bf16x8*)(Bs + (srow + 64) * LDR + scol) = b1;
    __syncthreads();
    bf16x8 af[4], bfv[4];
#pragma unroll
    for (int i = 0; i < 4; ++i)
      af[i] = *(const bf16x8*)(As + (wm + i * 16 + l16) * LDR + quad * 8);
#pragma unroll
    for (int j = 0; j < 4; ++j)
      bfv[j] = *(const bf16x8*)(Bs + (wn + j * 16 + l16) * LDR + quad * 8);
#pragma unroll
    for (int i = 0; i < 4; ++i)
#pragma unroll
      for (int j = 0; j < 4; ++j)
        acc[i][j] = __builtin_amdgcn_mfma_f32_16x16x32_bf16(af[i], bfv[j], acc[i][j], 0, 0, 0);
  }
  const int bidx = m0 >> 10;  // tile fully within one batch (128 | 1024)
#pragma unroll
  for (int j = 0; j < 4; ++j) {
    const int gn = n0 + wn + j * 16 + l16;
    const int which = gn >> 10, e = gn & 1023, h = e >> 6, d = e & 63;
    const float bb = bias[gn];
    const size_t bh = (size_t)(bidx * Hn + h);
#pragma unroll
    for (int i = 0; i < 4; ++i) {
#pragma unroll
      for (int r = 0; r < 4; ++r) {
        const int gm = m0 + wm + i * 16 + quad * 4 + r;
        const int s = gm & 1023;
        const bool msk = kpm[gm] != 0;
        const float val = msk ? 0.f : acc[i][j][r] + bb;
        const short o = f2b(val);
        if (which == 0)
          qb[(bh * 1024 + s) * 64 + d] = o;
        else if (which == 1)
          kb[(bh * 1024 + s) * 64 + d] = o;
        else
          vtb[(bh * 64 + d) * 1024 + s] = o;  // V transposed for PV B-operand
      }
    }
  }
}

// ---------------- scores = q @ k^T * scale + mask; kpm cols -> NEG; f32 raw out
__global__ __launch_bounds__(256) void scores_mfma_kernel(
    const short* __restrict__ qb, const short* __restrict__ kb,
    const float* __restrict__ mask, const int* __restrict__ kpm,
    float* __restrict__ wout) {
  __shared__ short As[128 * LDR];
  __shared__ short Bs[128 * LDR];
  const int bh = blockIdx.z, bidx = bh >> 4;
  const short* Aq = qb + (size_t)bh * 1024 * 64;
  const short* Bk = kb + (size_t)bh * 1024 * 64;
  const int tid = threadIdx.x;
  const int wave = tid >> 6, lane = tid & 63;
  const int quad = lane >> 4, l16 = lane & 15;
  const int wm = (wave >> 1) * 64, wn = (wave & 1) * 64;
  const int m0 = blockIdx.y * 128, n0 = blockIdx.x * 128;
  const int srow = tid >> 2, scol = (tid & 3) * 8;
  f32x4 acc[4][4];
#pragma unroll
  for (int i = 0; i < 4; ++i)
#pragma unroll
    for (int j = 0; j < 4; ++j) acc[i][j] = (f32x4){0.f, 0.f, 0.f, 0.f};
  for (int k0 = 0; k0 < 64; k0 += 32) {
    bf16x8 a0 = *(const bf16x8*)(Aq + (size_t)(m0 + srow) * 64 + k0 + scol);
    bf16x8 a1 = *(const bf16x8*)(Aq + (size_t)(m0 + srow + 64) * 64 + k0 + scol);
    bf16x8 b0 = *(const bf16x8*)(Bk + (size_t)(n0 + srow) * 64 + k0 + scol);
    bf16x8 b1 = *(const bf16x8*)(Bk + (size_t)(n0 + srow + 64) * 64 + k0 + scol);
    __syncthreads();
    *(bf16x8*)(As + srow * LDR + scol) = a0;
    *(bf16x8*)(As + (srow + 64) * LDR + scol) = a1;
    *(bf16x8*)(Bs + srow * LDR + scol) = b0;
    *(bf16x8*)(Bs + (srow + 64) * LDR + scol) = b1;
    __syncthreads();
    bf16x8 af[4], bfv[4];
#pragma unroll
    for (int i = 0; i < 4; ++i)
      af[i] = *(const bf16x8*)(As + (wm + i * 16 + l16) * LDR + quad * 8);
#pragma unroll
    for (int j = 0; j < 4; ++j)
      bfv[j] = *(const bf16x8*)(Bs + (wn + j * 16 + l16) * LDR + quad * 8);
#pragma unroll
    for (int i = 0; i < 4; ++i)
#pragma unroll
      for (int j = 0; j < 4; ++j)
        acc[i][j] = __builtin_amdgcn_mfma_f32_16x16x32_bf16(af[i], bfv[j], acc[i][j], 0, 0, 0);
  }
#pragma unroll
  for (int j = 0; j < 4; ++j) {
    const int gn = n0 + wn + j * 16 + l16;
    const int kp = kpm[bidx * 1024 + gn];
#pragma unroll
    for (int i = 0; i < 4; ++i) {
#pragma unroll
      for (int r = 0; r < 4; ++r) {
        const int gm = m0 + wm + i * 16 + quad * 4 + r;
        const float v =
            kp ? NEGV : fmaf(acc[i][j][r], SCALE, mask[(size_t)gm * 1024 + gn]);
        wout[((size_t)bh * 1024 + gm) * 1024 + gn] = v;
      }
    }
  }
}

// ---------------- in-place row softmax over last dim (1024)
__global__ __launch_bounds__(256) void softmax_kernel(float* __restrict__ w) {
  size_t row = blockIdx.x;
  float4* p = (float4*)(w + row * Sn);
  int tid = threadIdx.x;
  float4 v = p[tid];
  float mx = fmaxf(fmaxf(v.x, v.y), fmaxf(v.z, v.w));
#pragma unroll
  for (int off = 32; off > 0; off >>= 1) mx = fmaxf(mx, __shfl_down(mx, off));
  __shared__ float red[8];
  int wid = tid >> 6, lane = tid & 63;
  if (lane == 0) red[wid] = mx;
  __syncthreads();
  mx = fmaxf(fmaxf(red[0], red[1]), fmaxf(red[2], red[3]));
  v.x = __expf(v.x - mx); v.y = __expf(v.y - mx);
  v.z = __expf(v.z - mx); v.w = __expf(v.w - mx);
  float sm = v.x + v.y + v.z + v.w;
#pragma unroll
  for (int off = 32; off > 0; off >>= 1) sm += __shfl_down(sm, off);
  if (lane == 0) red[4 + wid] = sm;
  __syncthreads();
  sm = (red[4] + red[5]) + (red[6] + red[7]);
  float inv = 1.0f / sm;
  v.x *= inv; v.y *= inv; v.z *= inv; v.w *= inv;
  p[tid] = v;
}

// ---------------- ap = P @ V (per bh); stages f32 P -> bf16 LDS; writes bf16 ap (B,S,E)
__global__ __launch_bounds__(256) void pv_mfma_kernel(
    const float* __restrict__ p, const short* __restrict__ vtb,
    short* __restrict__ apb) {
  __shared__ short As[128 * LDR];
  __shared__ short Bs[64 * LDR];
  const int bh = blockIdx.y, bidx = bh >> 4, h = bh & 15;
  const float* P = p + (size_t)bh * 1024 * 1024;
  const short* V = vtb + (size_t)bh * 64 * 1024;
  const int tid = threadIdx.x;
  const int wave = tid >> 6, lane = tid & 63;
  const int quad = lane >> 4, l16 = lane & 15;
  const int m0 = blockIdx.x * 128;
  const int wrow = wave * 32;  // wave covers 32 rows x 64 cols
  const int srow = tid >> 2, scol = (tid & 3) * 8;
  f32x4 acc[2][4];
#pragma unroll
  for (int i = 0; i < 2; ++i)
#pragma unroll
    for (int j = 0; j < 4; ++j) acc[i][j] = (f32x4){0.f, 0.f, 0.f, 0.f};
  for (int k0 = 0; k0 < 1024; k0 += 32) {
    float4 p0 = *(const float4*)(P + (size_t)(m0 + srow) * 1024 + k0 + scol);
    float4 p1 = *(const float4*)(P + (size_t)(m0 + srow) * 1024 + k0 + scol + 4);
    float4 p2 = *(const float4*)(P + (size_t)(m0 + srow + 64) * 1024 + k0 + scol);
    float4 p3 = *(const float4*)(P + (size_t)(m0 + srow + 64) * 1024 + k0 + scol + 4);
    bf16x8 vv = *(const bf16x8*)(V + (size_t)srow * 1024 + k0 + scol);
    __syncthreads();
    bf16x8 pa, pb;
    pa[0] = f2b(p0.x); pa[1] = f2b(p0.y); pa[2] = f2b(p0.z); pa[3] = f2b(p0.w);
    pa[4] = f2b(p1.x); pa[5] = f2b(p1.y); pa[6] = f2b(p1.z); pa[7] = f2b(p1.w);
    pb[0] = f2b(p2.x); pb[1] = f2b(p2.y); pb[2] = f2b(p2.z); pb[3] = f2b(p2.w);
    pb[4] = f2b(p3.x); pb[5] = f2b(p3.y); pb[6] = f2b(p3.z); pb[7] = f2b(p3.w);
    *(bf16x8*)(As + srow * LDR + scol) = pa;
    *(bf16x8*)(As + (srow + 64) * LDR + scol) = pb;
    *(bf16x8*)(Bs + srow * LDR + scol) = vv;
    __syncthreads();
    bf16x8 af[2], bfv[4];
#pragma unroll
    for (int i = 0; i < 2; ++i)
      af[i] = *(const bf16x8*)(As + (wrow + i * 16 + l16) * LDR + quad * 8);
#pragma unroll
    for (int j = 0; j < 4; ++j)
      bfv[j] = *(const bf16x8*)(Bs + (j * 16 + l16) * LDR + quad * 8);
#pragma unroll
    for (int i = 0; i < 2; ++i)
#pragma unroll
      for (int j = 0; j < 4; ++j)
        acc[i][j] = __builtin_amdgcn_mfma_f32_16x16x32_bf16(af[i], bfv[j], acc[i][j], 0, 0, 0);
  }
#pragma unroll
  for (int i = 0; i < 2; ++i)
#pragma unroll
    for (int j = 0; j < 4; ++j)
#pragma unroll
      for (int r = 0; r < 4; ++r) {
        const int s = m0 + wrow + i * 16 + quad * 4 + r;
        const int d = j * 16 + l16;
        apb[((size_t)(bidx * 1024 + s)) * 1024 + h * 64 + d] = f2b(acc[i][j][r]);
      }
}

// ---------------- out = ap @ out_w^T + out_b (f32 out)
__global__ __launch_bounds__(256) void out_mfma_kernel(
    const short* __restrict__ ab, const short* __restrict__ wb,
    const float* __restrict__ bias, float* __restrict__ out) {
  __shared__ short As[128 * LDR];
  __shared__ short Bs[128 * LDR];
  const int tid = threadIdx.x;
  const int wave = tid >> 6, lane = tid & 63;
  const int quad = lane >> 4, l16 = lane & 15;
  const int wm = (wave >> 1) * 64, wn = (wave & 1) * 64;
  const int m0 = blockIdx.y * 128, n0 = blockIdx.x * 128;
  const int srow = tid >> 2, scol = (tid & 3) * 8;
  f32x4 acc[4][4];
#pragma unroll
  for (int i = 0; i < 4; ++i)
#pragma unroll
    for (int j = 0; j < 4; ++j) acc[i][j] = (f32x4){0.f, 0.f, 0.f, 0.f};
  for (int k0 = 0; k0 < 1024; k0 += 32) {
    bf16x8 a0 = *(const bf16x8*)(ab + (size_t)(m0 + srow) * 1024 + k0 + scol);
    bf16x8 a1 = *(const bf16x8*)(ab + (size_t)(m0 + srow + 64) * 1024 + k0 + scol);
    bf16x8 b0 = *(const bf16x8*)(wb + (size_t)(n0 + srow) * 1024 + k0 + scol);
    bf16x8 b1 = *(const bf16x8*)(wb + (size_t)(n0 + srow + 64) * 1024 + k0 + scol);
    __syncthreads();
    *(bf16x8*)(As + srow * LDR + scol) = a0;
    *(bf16x8*)(As + (srow + 64) * LDR + scol) = a1;
    *(bf16x8*)(Bs + srow * LDR + scol) = b0;
    *(bf16x8*)(Bs + (srow + 64) * LDR + scol) = b1;
    __syncthreads();
    bf16x8 af[4], bfv[4];
#pragma unroll
    for (int i = 0; i < 4; ++i)
      af[i] = *(const bf16x8*)(As + (wm + i * 16 + l16) * LDR + quad * 8);
#pragma unroll
    for (int j = 0; j < 4; ++j)
      bfv[j] = *(const bf16x8*)(Bs + (wn + j * 16 + l16) * LDR + quad * 8);
#pragma unroll
    for (int i = 0; i < 4; ++i)
#pragma unroll
      for (int j = 0; j < 4; ++j)
        acc[i][j] = __builtin_amdgcn_mfma_f32_16x16x32_bf16(af[i], bfv[j], acc[i][j], 0, 0, 0);
  }
#pragma unroll
  for (int j = 0; j < 4; ++j) {
    const int gn = n0 + wn + j * 16 + l16;
    const float bb = bias[gn];
#pragma unroll
    for (int i = 0; i < 4; ++i) {
#pragma unroll
      for (int r = 0; r < 4; ++r) {
        const int gm = m0 + wm + i * 16 + quad * 4 + r;
        out[(size_t)gm * 1024 + gn] = acc[i][j][r] + bb;
      }
    }
  }
}

extern "C" void kernel_launch(void* const* d_in, const int* in_sizes, int n_in,
                              void* d_out, int out_size, void* d_ws, size_t ws_size,
                              hipStream_t stream) {
  const float* x        = (const float*)d_in[0];
  const float* attnmask = (const float*)d_in[1];
  const int*   kpm      = (const int*)d_in[2];
  const float* qkv_w    = (const float*)d_in[3];
  const float* qkv_b    = (const float*)d_in[4];
  const float* out_w    = (const float*)d_in[5];
  const float* out_b    = (const float*)d_in[6];

  float* out     = (float*)d_out;               // [B,S,E] f32
  float* weights = out + (size_t)Bn * Sn * En;  // [B,H,S,S] f32

  short* ws  = (short*)d_ws;
  short* xb  = ws;                          // 4 M bf16
  short* wqb = xb  + ((size_t)4 << 20);     // 3 M
  short* owb = wqb + ((size_t)3 << 20);     // 1 M
  short* qb  = owb + ((size_t)1 << 20);     // 4 M (B,H,S,DK)
  short* kb  = qb  + ((size_t)4 << 20);     // 4 M (B,H,S,DK)
  short* vtb = kb  + ((size_t)4 << 20);     // 4 M (B,H,DK,S)
  short* apb = vtb + ((size_t)4 << 20);     // 4 M (B,S,E)

  cast_kernel<<<4096, 256, 0, stream>>>(x, xb, 1 << 20);
  cast_kernel<<<3072, 256, 0, stream>>>(qkv_w, wqb, 3 << 18);
  cast_kernel<<<1024, 256, 0, stream>>>(out_w, owb, 1 << 18);
  qkv_mfma_kernel<<<dim3(24, 32), 256, 0, stream>>>(xb, wqb, qkv_b, kpm, qb, kb, vtb);
  scores_mfma_kernel<<<dim3(8, 8, 64), 256, 0, stream>>>(qb, kb, attnmask, kpm, weights);
  softmax_kernel<<<dim3(Bn * Hn * Sn), 256, 0, stream>>>(weights);
  pv_mfma_kernel<<<dim3(8, 64), 256, 0, stream>>>(weights, vtb, apb);
  out_mfma_kernel<<<dim3(8, 32), 256, 0, stream>>>(apb, owb, out_b, out);
}

// Round 3
// 456.176 us; speedup vs baseline: 2.2611x; 1.4107x over previous
//
#include <hip/hip_runtime.h>
#include <math.h>

namespace {
constexpr int Bn = 4, Sn = 1024, En = 1024, Hn = 16, DKn = 64;
constexpr float NEGV = -10000.0f;
constexpr float SCALE = 0.125f;  // 1/sqrt(DK)
constexpr int LDR = 40;   // GEMM LDS stride (bf16): 2-way bank aliasing only
constexpr int LDK = 72;   // K-tile stride (64+8)
constexpr int LDP = 136;  // P/V tile stride (128+8)
}

typedef __attribute__((ext_vector_type(8))) short bf16x8;
typedef __attribute__((ext_vector_type(4))) float f32x4;

__device__ inline short f2b(float f) {
  unsigned u = __builtin_bit_cast(unsigned, f);
  u += 0x7fffu + ((u >> 16) & 1u);  // RNE
  return (short)(u >> 16);
}

// ---------------- f32 -> bf16 cast ----------------
__global__ __launch_bounds__(256) void cast_kernel(const float* __restrict__ in,
                                                   short* __restrict__ out, int n4) {
  int i = blockIdx.x * 256 + threadIdx.x;
  if (i < n4) {
    float4 v = ((const float4*)in)[i];
    short4 o = {f2b(v.x), f2b(v.y), f2b(v.z), f2b(v.w)};
    ((short4*)out)[i] = o;
  }
}

// ---------------- QKV: C = xb @ wqb^T + bias, mask rows, scatter bf16 q/k/vT
__global__ __launch_bounds__(256) void qkv_mfma_kernel(
    const short* __restrict__ xb, const short* __restrict__ wb,
    const float* __restrict__ bias, const int* __restrict__ kpm,
    short* __restrict__ qb, short* __restrict__ kb, short* __restrict__ vtb) {
  __shared__ short As[128 * LDR];
  __shared__ short Bs[128 * LDR];
  const int tid = threadIdx.x;
  const int wave = tid >> 6, lane = tid & 63;
  const int quad = lane >> 4, l16 = lane & 15;
  const int wm = (wave >> 1) * 64, wn = (wave & 1) * 64;
  const int m0 = blockIdx.y * 128, n0 = blockIdx.x * 128;
  const int srow = tid >> 2, scol = (tid & 3) * 8;
  f32x4 acc[4][4];
#pragma unroll
  for (int i = 0; i < 4; ++i)
#pragma unroll
    for (int j = 0; j < 4; ++j) acc[i][j] = (f32x4){0.f, 0.f, 0.f, 0.f};
  for (int k0 = 0; k0 < 1024; k0 += 32) {
    bf16x8 a0 = *(const bf16x8*)(xb + (size_t)(m0 + srow) * 1024 + k0 + scol);
    bf16x8 a1 = *(const bf16x8*)(xb + (size_t)(m0 + srow + 64) * 1024 + k0 + scol);
    bf16x8 b0 = *(const bf16x8*)(wb + (size_t)(n0 + srow) * 1024 + k0 + scol);
    bf16x8 b1 = *(const bf16x8*)(wb + (size_t)(n0 + srow + 64) * 1024 + k0 + scol);
    __syncthreads();
    *(bf16x8*)(As + srow * LDR + scol) = a0;
    *(bf16x8*)(As + (srow + 64) * LDR + scol) = a1;
    *(bf16x8*)(Bs + srow * LDR + scol) = b0;
    *(bf16x8*)(Bs + (srow + 64) * LDR + scol) = b1;
    __syncthreads();
    bf16x8 af[4], bfv[4];
#pragma unroll
    for (int i = 0; i < 4; ++i)
      af[i] = *(const bf16x8*)(As + (wm + i * 16 + l16) * LDR + quad * 8);
#pragma unroll
    for (int j = 0; j < 4; ++j)
      bfv[j] = *(const bf16x8*)(Bs + (wn + j * 16 + l16) * LDR + quad * 8);
#pragma unroll
    for (int i = 0; i < 4; ++i)
#pragma unroll
      for (int j = 0; j < 4; ++j)
        acc[i][j] = __builtin_amdgcn_mfma_f32_16x16x32_bf16(af[i], bfv[j], acc[i][j], 0, 0, 0);
  }
  const int bidx = m0 >> 10;
#pragma unroll
  for (int j = 0; j < 4; ++j) {
    const int gn = n0 + wn + j * 16 + l16;
    const int which = gn >> 10, e = gn & 1023, h = e >> 6, d = e & 63;
    const float bb = bias[gn];
    const size_t bh = (size_t)(bidx * Hn + h);
#pragma unroll
    for (int i = 0; i < 4; ++i) {
#pragma unroll
      for (int r = 0; r < 4; ++r) {
        const int gm = m0 + wm + i * 16 + quad * 4 + r;
        const int s = gm & 1023;
        const bool msk = kpm[gm] != 0;
        const float val = msk ? 0.f : acc[i][j][r] + bb;
        const short o = f2b(val);
        if (which == 0)
          qb[(bh * 1024 + s) * 64 + d] = o;
        else if (which == 1)
          kb[(bh * 1024 + s) * 64 + d] = o;
        else
          vtb[(bh * 64 + d) * 1024 + s] = o;
      }
    }
  }
}

// ---------------- fused scores+softmax+PV (two-pass flash, causal-aware)
// Block: 256 thr (4 waves), one (bh, 128 q-rows). Wave owns 32 q-rows.
__global__ __launch_bounds__(256, 2) void attn_fused_kernel(
    const short* __restrict__ qb, const short* __restrict__ kb,
    const short* __restrict__ vtb, const int* __restrict__ kpm,
    float* __restrict__ wout, short* __restrict__ apb) {
  __shared__ short Ks[128 * LDK];
  __shared__ short Vs[64 * LDP];
  __shared__ short Ps[128 * LDP];
  __shared__ int kpms[1024];
  const int bh = blockIdx.y, bidx = bh >> 4, h = bh & 15;
  // pair heavy/light q-tiles across the two co-resident block sets
  const int qt = (blockIdx.y >= 32) ? (7 - (int)blockIdx.x) : (int)blockIdx.x;
  const int q0 = qt * 128;
  const int ntiles = qt + 1;
  const short* Q = qb + (size_t)bh * Sn * DKn;
  const short* K = kb + (size_t)bh * Sn * DKn;
  const short* V = vtb + (size_t)bh * DKn * Sn;
  const int tid = threadIdx.x;
  const int wave = tid >> 6, lane = tid & 63, quad = lane >> 4, l16 = lane & 15;
  const int wrow = wave * 32;
  for (int i = tid; i < 1024; i += 256) kpms[i] = kpm[bidx * Sn + i];
  // Q fragments in registers: 32 rows x 64 K per wave
  bf16x8 qf[2][2];
#pragma unroll
  for (int i = 0; i < 2; ++i) {
    const int row = q0 + wrow + i * 16 + l16;
#pragma unroll
    for (int s = 0; s < 2; ++s)
      qf[i][s] = *(const bf16x8*)(Q + (size_t)row * 64 + s * 32 + quad * 8);
  }
  float m8[8], l8[8];
#pragma unroll
  for (int i = 0; i < 8; ++i) { m8[i] = -3.0e38f; l8[i] = 0.f; }

  // ---- pass A: exact row max + exp-sum (online)
  for (int t = 0; t < ntiles; ++t) {
    const int k0 = t * 128;
    __syncthreads();
    {
      const int r = tid >> 1, c0 = (tid & 1) * 32;
      const short* src = K + (size_t)(k0 + r) * 64 + c0;
      short* dst = Ks + r * LDK + c0;
#pragma unroll
      for (int u = 0; u < 4; ++u)
        *(bf16x8*)(dst + u * 8) = *(const bf16x8*)(src + u * 8);
    }
    __syncthreads();
    f32x4 sc[2][8];
#pragma unroll
    for (int i = 0; i < 2; ++i)
#pragma unroll
      for (int j = 0; j < 8; ++j) sc[i][j] = (f32x4){0.f, 0.f, 0.f, 0.f};
#pragma unroll
    for (int s = 0; s < 2; ++s) {
      bf16x8 bk[8];
#pragma unroll
      for (int j = 0; j < 8; ++j)
        bk[j] = *(const bf16x8*)(Ks + (j * 16 + l16) * LDK + s * 32 + quad * 8);
#pragma unroll
      for (int i = 0; i < 2; ++i)
#pragma unroll
        for (int j = 0; j < 8; ++j)
          sc[i][j] = __builtin_amdgcn_mfma_f32_16x16x32_bf16(qf[i][s], bk[j], sc[i][j], 0, 0, 0);
    }
    int cm[8];
#pragma unroll
    for (int j = 0; j < 8; ++j) cm[j] = kpms[k0 + j * 16 + l16];
    const bool diag = (t == qt);
#pragma unroll
    for (int i = 0; i < 2; ++i)
#pragma unroll
      for (int r = 0; r < 4; ++r) {
        const int idx = i * 4 + r;
        const int row = q0 + wrow + i * 16 + quad * 4 + r;
        float sv[8];
        float tmax = -3.0e38f;
#pragma unroll
        for (int j = 0; j < 8; ++j) {
          const int col = k0 + j * 16 + l16;
          float s = sc[i][j][r] * SCALE;
          if (cm[j]) s = NEGV;
          if (diag && col > row) s = NEGV;
          sv[j] = s;
          tmax = fmaxf(tmax, s);
        }
#pragma unroll
        for (int d = 1; d < 16; d <<= 1) tmax = fmaxf(tmax, __shfl_xor(tmax, d));
        const float mo = m8[idx];
        const float mn = fmaxf(mo, tmax);
        float sum = 0.f;
#pragma unroll
        for (int j = 0; j < 8; ++j) sum += __expf(sv[j] - mn);
#pragma unroll
        for (int d = 1; d < 16; d <<= 1) sum += __shfl_xor(sum, d);
        l8[idx] = l8[idx] * __expf(mo - mn) + sum;
        m8[idx] = mn;
      }
  }
  float linv[8];
#pragma unroll
  for (int i = 0; i < 8; ++i) linv[i] = 1.0f / l8[i];

  // ---- pass B: recompute scores, write normalized P, accumulate O = P @ V
  f32x4 oacc[2][4];
#pragma unroll
  for (int i = 0; i < 2; ++i)
#pragma unroll
    for (int j = 0; j < 4; ++j) oacc[i][j] = (f32x4){0.f, 0.f, 0.f, 0.f};
  for (int t = 0; t < ntiles; ++t) {
    const int k0 = t * 128;
    __syncthreads();
    {
      const int r = tid >> 1, c0 = (tid & 1) * 32;
      const short* src = K + (size_t)(k0 + r) * 64 + c0;
      short* dst = Ks + r * LDK + c0;
#pragma unroll
      for (int u = 0; u < 4; ++u)
        *(bf16x8*)(dst + u * 8) = *(const bf16x8*)(src + u * 8);
    }
    {
      const int vr = tid >> 2, c0 = (tid & 3) * 32;
      const short* src = V + (size_t)vr * Sn + k0 + c0;
      short* dst = Vs + vr * LDP + c0;
#pragma unroll
      for (int u = 0; u < 4; ++u)
        *(bf16x8*)(dst + u * 8) = *(const bf16x8*)(src + u * 8);
    }
    __syncthreads();
    f32x4 sc[2][8];
#pragma unroll
    for (int i = 0; i < 2; ++i)
#pragma unroll
      for (int j = 0; j < 8; ++j) sc[i][j] = (f32x4){0.f, 0.f, 0.f, 0.f};
#pragma unroll
    for (int s = 0; s < 2; ++s) {
      bf16x8 bk[8];
#pragma unroll
      for (int j = 0; j < 8; ++j)
        bk[j] = *(const bf16x8*)(Ks + (j * 16 + l16) * LDK + s * 32 + quad * 8);
#pragma unroll
      for (int i = 0; i < 2; ++i)
#pragma unroll
        for (int j = 0; j < 8; ++j)
          sc[i][j] = __builtin_amdgcn_mfma_f32_16x16x32_bf16(qf[i][s], bk[j], sc[i][j], 0, 0, 0);
    }
    int cm[8];
#pragma unroll
    for (int j = 0; j < 8; ++j) cm[j] = kpms[k0 + j * 16 + l16];
    const bool diag = (t == qt);
#pragma unroll
    for (int i = 0; i < 2; ++i)
#pragma unroll
      for (int r = 0; r < 4; ++r) {
        const int idx = i * 4 + r;
        const int row = q0 + wrow + i * 16 + quad * 4 + r;
        float* wr = wout + ((size_t)bh * Sn + row) * Sn;
        const int rloc = wrow + i * 16 + quad * 4 + r;
#pragma unroll
        for (int j = 0; j < 8; ++j) {
          const int col = k0 + j * 16 + l16;
          float s = sc[i][j][r] * SCALE;
          if (cm[j]) s = NEGV;
          if (diag && col > row) s = NEGV;
          const float p = __expf(s - m8[idx]) * linv[idx];
          wr[col] = p;
          Ps[rloc * LDP + j * 16 + l16] = f2b(p);
        }
      }
    __syncthreads();
#pragma unroll
    for (int s4 = 0; s4 < 4; ++s4) {
      bf16x8 pa[2], vb[4];
#pragma unroll
      for (int i = 0; i < 2; ++i)
        pa[i] = *(const bf16x8*)(Ps + (wrow + i * 16 + l16) * LDP + s4 * 32 + quad * 8);
#pragma unroll
      for (int j = 0; j < 4; ++j)
        vb[j] = *(const bf16x8*)(Vs + (j * 16 + l16) * LDP + s4 * 32 + quad * 8);
#pragma unroll
      for (int i = 0; i < 2; ++i)
#pragma unroll
        for (int j = 0; j < 4; ++j)
          oacc[i][j] = __builtin_amdgcn_mfma_f32_16x16x32_bf16(pa[i], vb[j], oacc[i][j], 0, 0, 0);
    }
  }
  // zero-fill the causal upper part of this block's weight rows (coalesced)
  const int zc0 = ntiles * 128;
  const int span4 = (Sn - zc0) >> 2;
  const float4 z4 = {0.f, 0.f, 0.f, 0.f};
  for (int r = 0; r < 128; ++r)
    for (int c = tid; c < span4; c += 256)
      ((float4*)(wout + ((size_t)bh * Sn + q0 + r) * Sn + zc0))[c] = z4;
  // write O (bf16 attn_pre, [B,S,E])
#pragma unroll
  for (int i = 0; i < 2; ++i)
#pragma unroll
    for (int j = 0; j < 4; ++j)
#pragma unroll
      for (int r = 0; r < 4; ++r) {
        const int s = q0 + wrow + i * 16 + quad * 4 + r;
        apb[((size_t)(bidx * Sn + s)) * En + h * 64 + j * 16 + l16] = f2b(oacc[i][j][r]);
      }
}

// ---------------- out = ap @ out_w^T + out_b (f32 out)
__global__ __launch_bounds__(256) void out_mfma_kernel(
    const short* __restrict__ ab, const short* __restrict__ wb,
    const float* __restrict__ bias, float* __restrict__ out) {
  __shared__ short As[128 * LDR];
  __shared__ short Bs[128 * LDR];
  const int tid = threadIdx.x;
  const int wave = tid >> 6, lane = tid & 63;
  const int quad = lane >> 4, l16 = lane & 15;
  const int wm = (wave >> 1) * 64, wn = (wave & 1) * 64;
  const int m0 = blockIdx.y * 128, n0 = blockIdx.x * 128;
  const int srow = tid >> 2, scol = (tid & 3) * 8;
  f32x4 acc[4][4];
#pragma unroll
  for (int i = 0; i < 4; ++i)
#pragma unroll
    for (int j = 0; j < 4; ++j) acc[i][j] = (f32x4){0.f, 0.f, 0.f, 0.f};
  for (int k0 = 0; k0 < 1024; k0 += 32) {
    bf16x8 a0 = *(const bf16x8*)(ab + (size_t)(m0 + srow) * 1024 + k0 + scol);
    bf16x8 a1 = *(const bf16x8*)(ab + (size_t)(m0 + srow + 64) * 1024 + k0 + scol);
    bf16x8 b0 = *(const bf16x8*)(wb + (size_t)(n0 + srow) * 1024 + k0 + scol);
    bf16x8 b1 = *(const bf16x8*)(wb + (size_t)(n0 + srow + 64) * 1024 + k0 + scol);
    __syncthreads();
    *(bf16x8*)(As + srow * LDR + scol) = a0;
    *(bf16x8*)(As + (srow + 64) * LDR + scol) = a1;
    *(bf16x8*)(Bs + srow * LDR + scol) = b0;
    *(bf16x8*)(Bs + (srow + 64) * LDR + scol) = b1;
    __syncthreads();
    bf16x8 af[4], bfv[4];
#pragma unroll
    for (int i = 0; i < 4; ++i)
      af[i] = *(const bf16x8*)(As + (wm + i * 16 + l16) * LDR + quad * 8);
#pragma unroll
    for (int j = 0; j < 4; ++j)
      bfv[j] = *(const bf16x8*)(Bs + (wn + j * 16 + l16) * LDR + quad * 8);
#pragma unroll
    for (int i = 0; i < 4; ++i)
#pragma unroll
      for (int j = 0; j < 4; ++j)
        acc[i][j] = __builtin_amdgcn_mfma_f32_16x16x32_bf16(af[i], bfv[j], acc[i][j], 0, 0, 0);
  }
#pragma unroll
  for (int j = 0; j < 4; ++j) {
    const int gn = n0 + wn + j * 16 + l16;
    const float bb = bias[gn];
#pragma unroll
    for (int i = 0; i < 4; ++i) {
#pragma unroll
      for (int r = 0; r < 4; ++r) {
        const int gm = m0 + wm + i * 16 + quad * 4 + r;
        out[(size_t)gm * 1024 + gn] = acc[i][j][r] + bb;
      }
    }
  }
}

extern "C" void kernel_launch(void* const* d_in, const int* in_sizes, int n_in,
                              void* d_out, int out_size, void* d_ws, size_t ws_size,
                              hipStream_t stream) {
  const float* x        = (const float*)d_in[0];
  const int*   kpm      = (const int*)d_in[2];
  const float* qkv_w    = (const float*)d_in[3];
  const float* qkv_b    = (const float*)d_in[4];
  const float* out_w    = (const float*)d_in[5];
  const float* out_b    = (const float*)d_in[6];

  float* out     = (float*)d_out;               // [B,S,E] f32
  float* weights = out + (size_t)Bn * Sn * En;  // [B,H,S,S] f32

  short* ws  = (short*)d_ws;
  short* xb  = ws;                          // 4 M bf16
  short* wqb = xb  + ((size_t)4 << 20);     // 3 M
  short* owb = wqb + ((size_t)3 << 20);     // 1 M
  short* qb  = owb + ((size_t)1 << 20);     // 4 M (B,H,S,DK)
  short* kb  = qb  + ((size_t)4 << 20);     // 4 M (B,H,S,DK)
  short* vtb = kb  + ((size_t)4 << 20);     // 4 M (B,H,DK,S)
  short* apb = vtb + ((size_t)4 << 20);     // 4 M (B,S,E)

  cast_kernel<<<4096, 256, 0, stream>>>(x, xb, 1 << 20);
  cast_kernel<<<3072, 256, 0, stream>>>(qkv_w, wqb, 3 << 18);
  cast_kernel<<<1024, 256, 0, stream>>>(out_w, owb, 1 << 18);
  qkv_mfma_kernel<<<dim3(24, 32), 256, 0, stream>>>(xb, wqb, qkv_b, kpm, qb, kb, vtb);
  attn_fused_kernel<<<dim3(8, 64), 256, 0, stream>>>(qb, kb, vtb, kpm, weights, apb);
  out_mfma_kernel<<<dim3(8, 32), 256, 0, stream>>>(apb, owb, out_b, out);
}